// Round 1
// baseline (2392.630 us; speedup 1.0000x reference)
//
#include <hip/hip_runtime.h>
#include <math.h>

#define N_NODES 100000
#define N_FEAT  512
#define HIDDEN  256
#define N_CLS   40
#define N_EDGES 1600000
#define K_HOPS  10

// ---------------------------------------------------------------- prep kernels

__global__ __launch_bounds__(256) void init_deg_kernel(int* __restrict__ deg) {
    int v = blockIdx.x * 256 + threadIdx.x;
    if (v < N_NODES) deg[v] = 1;  // self-loop
}

__global__ __launch_bounds__(256) void count_dst_kernel(const int* __restrict__ dst,
                                                        int* __restrict__ deg) {
    int e = blockIdx.x * 256 + threadIdx.x;
    if (e < N_EDGES) atomicAdd(&deg[dst[e]], 1);
}

__global__ __launch_bounds__(256) void rsqrt_deg_kernel(const int* __restrict__ deg,
                                                        float* __restrict__ d) {
    int v = blockIdx.x * 256 + threadIdx.x;
    if (v < N_NODES) d[v] = rsqrtf((float)deg[v]);
}

// exclusive scan of deg[0..N) -> rowptr[0..N], plus cursor copy. Single block.
__global__ __launch_bounds__(1024) void scan_kernel(const int* __restrict__ deg,
                                                    int* __restrict__ rowptr,
                                                    int* __restrict__ cursor) {
    __shared__ int part[1024];
    const int t = threadIdx.x;
    const int CH = 98;  // 1024*98 = 100352 >= 100001
    int base = t * CH;
    int run = 0;
    for (int i = 0; i < CH; ++i) {
        int idx = base + i;
        if (idx < N_NODES) run += deg[idx];
    }
    part[t] = run;
    __syncthreads();
    if (t == 0) {
        int s = 0;
        for (int i = 0; i < 1024; ++i) { int v = part[i]; part[i] = s; s += v; }
    }
    __syncthreads();
    run = part[t];
    for (int i = 0; i < CH; ++i) {
        int idx = base + i;
        if (idx <= N_NODES) rowptr[idx] = run;
        if (idx < N_NODES) { cursor[idx] = run; run += deg[idx]; }
    }
}

__global__ __launch_bounds__(256) void scatter_edges_kernel(const int* __restrict__ src,
                                                            const int* __restrict__ dst,
                                                            const float* __restrict__ d,
                                                            int* __restrict__ cursor,
                                                            int* __restrict__ esrc,
                                                            float* __restrict__ enorm) {
    int e = blockIdx.x * 256 + threadIdx.x;
    if (e >= N_EDGES) return;
    int u = src[e], v = dst[e];
    int pos = atomicAdd(&cursor[v], 1);
    esrc[pos] = u;
    enorm[pos] = d[u] * d[v];
}

__global__ __launch_bounds__(256) void scatter_self_kernel(const float* __restrict__ d,
                                                           int* __restrict__ cursor,
                                                           int* __restrict__ esrc,
                                                           float* __restrict__ enorm) {
    int v = blockIdx.x * 256 + threadIdx.x;
    if (v >= N_NODES) return;
    int pos = atomicAdd(&cursor[v], 1);
    esrc[pos] = v;
    float dv = d[v];
    enorm[pos] = dv * dv;
}

// ---------------------------------------------------------------- fused MLP
// h = relu(feat@W1+b1)@W2+b2 ; also TH = temp[0]*h (written to d_out).
// Block: 256 threads, 64 rows. Phase A: 64x64 hidden col-tile via LDS tiling,
// 4x4 register micro-tile/thread. Phase B: fold col-tile into [64 x 40] output
// accumulators (thread owns 1 row x 10 classes).
__global__ __launch_bounds__(256) void mlp_kernel(const float* __restrict__ feat,
                                                  const float* __restrict__ W1,
                                                  const float* __restrict__ b1,
                                                  const float* __restrict__ W2,
                                                  const float* __restrict__ b2,
                                                  const float* __restrict__ temp,
                                                  float* __restrict__ h,
                                                  float* __restrict__ TH) {
    __shared__ float sA[64][68];  // feat tile, [k][row]
    __shared__ float sB[64][68];  // W1 tile,  [k][col]
    __shared__ float sH[64][68];  // relu(hid), [col][row]

    const int tid = threadIdx.x;
    const int rbase = blockIdx.x * 64;
    const int tx = tid & 15;   // row group (phase A): rows tx*4..tx*4+3
    const int ty = tid >> 4;   // col group (phase A): cols ty*4..ty*4+3
    const int br = tid >> 2;        // phase B row 0..63
    const int bc = (tid & 3) * 10;  // phase B class offset

    float outacc[10];
#pragma unroll
    for (int i = 0; i < 10; ++i) outacc[i] = 0.f;

    for (int ct = 0; ct < 4; ++ct) {
        float acc[4][4];
#pragma unroll
        for (int i = 0; i < 4; ++i)
#pragma unroll
            for (int j = 0; j < 4; ++j) acc[i][j] = 0.f;

        for (int kt = 0; kt < 8; ++kt) {
            __syncthreads();  // previous tile fully consumed
#pragma unroll
            for (int p = 0; p < 16; ++p) {
                int lin = p * 256 + tid;
                int k = lin & 63, r = lin >> 6;
                int row = rbase + r;
                float v = 0.f;
                if (row < N_NODES) v = feat[row * N_FEAT + kt * 64 + k];
                sA[k][r] = v;
            }
#pragma unroll
            for (int p = 0; p < 16; ++p) {
                int lin = p * 256 + tid;
                int c = lin & 63, k = lin >> 6;
                sB[k][c] = W1[(kt * 64 + k) * HIDDEN + ct * 64 + c];
            }
            __syncthreads();
#pragma unroll 8
            for (int k = 0; k < 64; ++k) {
                float4 a = *(const float4*)&sA[k][tx * 4];
                float4 b = *(const float4*)&sB[k][ty * 4];
                acc[0][0] += a.x * b.x; acc[0][1] += a.x * b.y; acc[0][2] += a.x * b.z; acc[0][3] += a.x * b.w;
                acc[1][0] += a.y * b.x; acc[1][1] += a.y * b.y; acc[1][2] += a.y * b.z; acc[1][3] += a.y * b.w;
                acc[2][0] += a.z * b.x; acc[2][1] += a.z * b.y; acc[2][2] += a.z * b.z; acc[2][3] += a.z * b.w;
                acc[3][0] += a.w * b.x; acc[3][1] += a.w * b.y; acc[3][2] += a.w * b.z; acc[3][3] += a.w * b.w;
            }
        }
        __syncthreads();
        // bias + relu, stage to LDS transposed for phase B
#pragma unroll
        for (int j = 0; j < 4; ++j) {
            float bb = b1[ct * 64 + ty * 4 + j];
#pragma unroll
            for (int i = 0; i < 4; ++i) {
                float v = acc[i][j] + bb;
                sH[ty * 4 + j][tx * 4 + i] = v > 0.f ? v : 0.f;
            }
        }
        __syncthreads();
        // phase B: outacc[r][bc..bc+9] += hid[r][j] * W2[jglob][c]
#pragma unroll 4
        for (int j = 0; j < 64; ++j) {
            float hv = sH[j][br];
            const float* w2row = W2 + (ct * 64 + j) * N_CLS + bc;
#pragma unroll
            for (int i = 0; i < 10; ++i) outacc[i] += hv * w2row[i];
        }
    }

    int row = rbase + br;
    if (row < N_NODES) {
        float t0 = temp[0];
#pragma unroll
        for (int i = 0; i < 10; ++i) {
            float v = outacc[i] + b2[bc + i];
            h[row * N_CLS + bc + i] = v;
            TH[row * N_CLS + bc + i] = t0 * v;
        }
    }
}

// ---------------------------------------------------------------- propagation
// Pull-based: node v sums h[u]*norm over its CSR in-edges (self-loop included).
// 8 threads per node, 5 classes each. TH += temp[kidx]*hnew.
__global__ __launch_bounds__(256) void prop_kernel(const float* __restrict__ h,
                                                   float* __restrict__ hn,
                                                   const int* __restrict__ rowptr,
                                                   const int* __restrict__ esrc,
                                                   const float* __restrict__ enorm,
                                                   float* __restrict__ TH,
                                                   const float* __restrict__ temp,
                                                   int kidx) {
    int gid = blockIdx.x * 256 + threadIdx.x;
    int v = gid >> 3;
    if (v >= N_NODES) return;
    int c0 = (gid & 7) * 5;
    int s = rowptr[v], e = rowptr[v + 1];
    float acc0 = 0.f, acc1 = 0.f, acc2 = 0.f, acc3 = 0.f, acc4 = 0.f;
    for (int j = s; j < e; ++j) {
        int u = esrc[j];
        float w = enorm[j];
        const float* hu = h + u * N_CLS + c0;
        acc0 += w * hu[0];
        acc1 += w * hu[1];
        acc2 += w * hu[2];
        acc3 += w * hu[3];
        acc4 += w * hu[4];
    }
    float tk = temp[kidx];
    float* pn = hn + v * N_CLS + c0;
    float* pt = TH + v * N_CLS + c0;
    pn[0] = acc0; pt[0] += tk * acc0;
    pn[1] = acc1; pt[1] += tk * acc1;
    pn[2] = acc2; pt[2] += tk * acc2;
    pn[3] = acc3; pt[3] += tk * acc3;
    pn[4] = acc4; pt[4] += tk * acc4;
}

// ---------------------------------------------------------------- log_softmax
// One wave (64 lanes) per row of 40; lanes >=40 padded.
__global__ __launch_bounds__(256) void lsm_kernel(float* __restrict__ out) {
    int wid = (blockIdx.x * 256 + threadIdx.x) >> 6;
    int lane = threadIdx.x & 63;
    if (wid >= N_NODES) return;
    float x = (lane < N_CLS) ? out[wid * N_CLS + lane] : -INFINITY;
    float m = x;
#pragma unroll
    for (int o = 32; o > 0; o >>= 1) m = fmaxf(m, __shfl_xor(m, o, 64));
    float e = (lane < N_CLS) ? expf(x - m) : 0.f;
    float s = e;
#pragma unroll
    for (int o = 32; o > 0; o >>= 1) s += __shfl_xor(s, o, 64);
    float r = x - m - logf(s);
    if (lane < N_CLS) out[wid * N_CLS + lane] = r;
}

// ---------------------------------------------------------------- launch

extern "C" void kernel_launch(void* const* d_in, const int* in_sizes, int n_in,
                              void* d_out, int out_size, void* d_ws, size_t ws_size,
                              hipStream_t stream) {
    const float* feat = (const float*)d_in[0];
    const float* W1   = (const float*)d_in[1];
    const float* b1   = (const float*)d_in[2];
    const float* W2   = (const float*)d_in[3];
    const float* b2   = (const float*)d_in[4];
    const float* temp = (const float*)d_in[5];
    const int*   src  = (const int*)d_in[6];
    const int*   dst  = (const int*)d_in[7];
    float* out = (float*)d_out;

    // workspace layout (bytes, all 16B-aligned); total ~47.2 MB
    char* ws = (char*)d_ws;
    int*   deg    = (int*)(ws + 0);          //  400000 B
    float* dnorm  = (float*)(ws + 400000);   //  400000 B
    int*   rowptr = (int*)(ws + 800000);     //  400004 B
    int*   cursor = (int*)(ws + 1200016);    //  400000 B
    int*   esrc   = (int*)(ws + 1600032);    // 6800000 B (1.7M edges incl self)
    float* enorm  = (float*)(ws + 8400032);  // 6800000 B
    float* h0     = (float*)(ws + 15200032); // 16000000 B
    float* h1     = (float*)(ws + 31200032); // 16000000 B  -> end 47200032

    init_deg_kernel<<<(N_NODES + 255) / 256, 256, 0, stream>>>(deg);
    count_dst_kernel<<<(N_EDGES + 255) / 256, 256, 0, stream>>>(dst, deg);
    rsqrt_deg_kernel<<<(N_NODES + 255) / 256, 256, 0, stream>>>(deg, dnorm);
    scan_kernel<<<1, 1024, 0, stream>>>(deg, rowptr, cursor);
    scatter_edges_kernel<<<(N_EDGES + 255) / 256, 256, 0, stream>>>(src, dst, dnorm, cursor,
                                                                    esrc, enorm);
    scatter_self_kernel<<<(N_NODES + 255) / 256, 256, 0, stream>>>(dnorm, cursor, esrc, enorm);

    mlp_kernel<<<(N_NODES + 63) / 64, 256, 0, stream>>>(feat, W1, b1, W2, b2, temp, h0, out);

    float* hc = h0;
    float* hn = h1;
    for (int k = 0; k < K_HOPS; ++k) {
        prop_kernel<<<(N_NODES * 8) / 256, 256, 0, stream>>>(hc, hn, rowptr, esrc, enorm, out,
                                                             temp, k + 1);
        float* t = hc; hc = hn; hn = t;
    }

    lsm_kernel<<<(N_NODES / 4), 256, 0, stream>>>(out);
}

// Round 2
// 1382.238 us; speedup vs baseline: 1.7310x; 1.7310x over previous
//
#include <hip/hip_runtime.h>
#include <math.h>

#define N_NODES 100000
#define N_FEAT  512
#define HIDDEN  256
#define N_CLS   40
#define N_EDGES 1600000
#define K_HOPS  10

typedef __attribute__((ext_vector_type(8))) short short8;   // 8 bf16 (one MFMA frag)
typedef __attribute__((ext_vector_type(4))) float f4_t;

__device__ __forceinline__ short f2bf(float f) {
    union { float f; unsigned u; } x; x.f = f;
    unsigned r = x.u + 0x7fffu + ((x.u >> 16) & 1u);  // RNE
    return (short)(r >> 16);
}

// ---------------------------------------------------------------- prep kernels

__global__ __launch_bounds__(256) void init_deg_kernel(int* __restrict__ deg) {
    int v = blockIdx.x * 256 + threadIdx.x;
    if (v < N_NODES) deg[v] = 1;  // self-loop
}

__global__ __launch_bounds__(256) void count_dst_kernel(const int* __restrict__ dst,
                                                        int* __restrict__ deg) {
    int e = blockIdx.x * 256 + threadIdx.x;
    if (e < N_EDGES) atomicAdd(&deg[dst[e]], 1);
}

__global__ __launch_bounds__(256) void rsqrt_deg_kernel(const int* __restrict__ deg,
                                                        float* __restrict__ d) {
    int v = blockIdx.x * 256 + threadIdx.x;
    if (v < N_NODES) d[v] = rsqrtf((float)deg[v]);
}

// exclusive scan of deg[0..N) -> rowptr[0..N], plus cursor copy. Single block.
__global__ __launch_bounds__(1024) void scan_kernel(const int* __restrict__ deg,
                                                    int* __restrict__ rowptr,
                                                    int* __restrict__ cursor) {
    __shared__ int part[1024];
    const int t = threadIdx.x;
    const int CH = 98;  // 1024*98 = 100352 >= 100001
    int base = t * CH;
    int run = 0;
    for (int i = 0; i < CH; ++i) {
        int idx = base + i;
        if (idx < N_NODES) run += deg[idx];
    }
    part[t] = run;
    __syncthreads();
    if (t == 0) {
        int s = 0;
        for (int i = 0; i < 1024; ++i) { int v = part[i]; part[i] = s; s += v; }
    }
    __syncthreads();
    run = part[t];
    for (int i = 0; i < CH; ++i) {
        int idx = base + i;
        if (idx <= N_NODES) rowptr[idx] = run;
        if (idx < N_NODES) { cursor[idx] = run; run += deg[idx]; }
    }
}

__global__ __launch_bounds__(256) void scatter_edges_kernel(const int* __restrict__ src,
                                                            const int* __restrict__ dst,
                                                            const float* __restrict__ d,
                                                            int* __restrict__ cursor,
                                                            int* __restrict__ esrc,
                                                            float* __restrict__ enorm) {
    int e = blockIdx.x * 256 + threadIdx.x;
    if (e >= N_EDGES) return;
    int u = src[e], v = dst[e];
    int pos = atomicAdd(&cursor[v], 1);
    esrc[pos] = u;
    enorm[pos] = d[u] * d[v];
}

__global__ __launch_bounds__(256) void scatter_self_kernel(const float* __restrict__ d,
                                                           int* __restrict__ cursor,
                                                           int* __restrict__ esrc,
                                                           float* __restrict__ enorm) {
    int v = blockIdx.x * 256 + threadIdx.x;
    if (v >= N_NODES) return;
    int pos = atomicAdd(&cursor[v], 1);
    esrc[pos] = v;
    float dv = d[v];
    enorm[pos] = dv * dv;
}

// W1 [512][256] f32 -> W1T [256][512] bf16 (col-major: per-col k contiguous)
__global__ __launch_bounds__(256) void cvt_w1_kernel(const float* __restrict__ W1,
                                                     short* __restrict__ W1T) {
    int lin = blockIdx.x * 256 + threadIdx.x;  // 131072
    int k = lin >> 8, n = lin & 255;
    W1T[n * 512 + k] = f2bf(W1[lin]);
}

// W2 [256][40] f32 -> W2T [64][256] bf16, rows >=40 zero
__global__ __launch_bounds__(256) void cvt_w2_kernel(const float* __restrict__ W2,
                                                     short* __restrict__ W2T) {
    int lin = blockIdx.x * 256 + threadIdx.x;  // 16384
    int n = lin >> 8, k = lin & 255;
    W2T[lin] = (n < N_CLS) ? f2bf(W2[k * N_CLS + n]) : (short)0;
}

// ---------------------------------------------------------------- fused MLP (MFMA)
// Block = 256 thr (4 waves), 64 rows. Phase A: h1 = relu(feat@W1+b1) -> sH (bf16).
// Phase B: out = sH @ W2 + b2 -> h, TH. 16x16x32 bf16 MFMA throughout.
__global__ __launch_bounds__(256) void mlp_kernel(const float* __restrict__ feat,
                                                  const short* __restrict__ W1T,
                                                  const float* __restrict__ b1,
                                                  const short* __restrict__ W2T,
                                                  const float* __restrict__ b2,
                                                  const float* __restrict__ temp,
                                                  float* __restrict__ h,
                                                  float* __restrict__ TH) {
    __shared__ union {
        struct { short A[64][72]; short B[256][72]; } a;  // 9216 + 36864 B
        short W2s[48][264];                               // 25344 B
    } uS;
    __shared__ short sH[64][264];                         // 33792 B  (total 79872)

    const int tid = threadIdx.x;
    const int rbase = blockIdx.x * 64;
    const int lane = tid & 63;
    const int wv = tid >> 6;       // wave 0..3
    const int quad = lane >> 4;    // 0..3
    const int l15 = lane & 15;

    f4_t acc[4][4];  // [m-tile][n-tile]
#pragma unroll
    for (int m = 0; m < 4; ++m)
#pragma unroll
        for (int n = 0; n < 4; ++n) acc[m][n] = (f4_t)0.f;

    // ---- Phase A: K = 512 in 8 chunks of 64
    const int arow = tid >> 2;     // staging row 0..63
    const int akq = tid & 3;       // k quarter (16 floats)
    for (int kt = 0; kt < 8; ++kt) {
        __syncthreads();
        {   // stage A: feat fp32 -> bf16 LDS [row][k], pad 72
            int grow = rbase + arow;
            f4_t f0 = (f4_t)0.f, f1 = (f4_t)0.f, f2 = (f4_t)0.f, f3 = (f4_t)0.f;
            if (grow < N_NODES) {
                const f4_t* p = (const f4_t*)(feat + grow * N_FEAT + kt * 64 + akq * 16);
                f0 = p[0]; f1 = p[1]; f2 = p[2]; f3 = p[3];
            }
            short8 lo, hi;
            lo[0]=f2bf(f0[0]); lo[1]=f2bf(f0[1]); lo[2]=f2bf(f0[2]); lo[3]=f2bf(f0[3]);
            lo[4]=f2bf(f1[0]); lo[5]=f2bf(f1[1]); lo[6]=f2bf(f1[2]); lo[7]=f2bf(f1[3]);
            hi[0]=f2bf(f2[0]); hi[1]=f2bf(f2[1]); hi[2]=f2bf(f2[2]); hi[3]=f2bf(f2[3]);
            hi[4]=f2bf(f3[0]); hi[5]=f2bf(f3[1]); hi[6]=f2bf(f3[2]); hi[7]=f2bf(f3[3]);
            short8* dstp = (short8*)&uS.a.A[arow][akq * 16];
            dstp[0] = lo; dstp[1] = hi;
        }
        // stage B: W1T[col][kt*64 .. +63] -> LDS [col][k], pad 72
#pragma unroll
        for (int p = 0; p < 8; ++p) {
            int lin = p * 256 + tid;           // 2048 chunks of 8 bf16
            int col = lin >> 3, kc = lin & 7;
            *(short8*)&uS.a.B[col][kc * 8] =
                *(const short8*)(W1T + col * 512 + kt * 64 + kc * 8);
        }
        __syncthreads();
#pragma unroll
        for (int kk = 0; kk < 64; kk += 32) {
            short8 af[4], bf[4];
#pragma unroll
            for (int m = 0; m < 4; ++m)
                af[m] = *(const short8*)&uS.a.A[m * 16 + l15][kk + quad * 8];
#pragma unroll
            for (int n = 0; n < 4; ++n)
                bf[n] = *(const short8*)&uS.a.B[wv * 64 + n * 16 + l15][kk + quad * 8];
#pragma unroll
            for (int m = 0; m < 4; ++m)
#pragma unroll
                for (int n = 0; n < 4; ++n)
                    acc[m][n] = __builtin_amdgcn_mfma_f32_16x16x32_bf16(af[m], bf[n],
                                                                        acc[m][n], 0, 0, 0);
        }
    }
    __syncthreads();  // uS.a fully consumed before W2s overwrite

    // epilogue A: bias + relu -> sH bf16 [row][col] pad 264
#pragma unroll
    for (int n = 0; n < 4; ++n) {
        int col = wv * 64 + n * 16 + l15;
        float bb = b1[col];
#pragma unroll
        for (int m = 0; m < 4; ++m)
#pragma unroll
            for (int r = 0; r < 4; ++r) {
                float v = acc[m][n][r] + bb;
                sH[m * 16 + quad * 4 + r][col] = f2bf(v > 0.f ? v : 0.f);
            }
    }
    // stage W2s: [48][256] bf16 -> LDS pad 264
#pragma unroll
    for (int p = 0; p < 6; ++p) {
        int lin = p * 256 + tid;               // 1536 chunks of 8 bf16
        int n = lin >> 5, kc = lin & 31;
        *(short8*)&uS.W2s[n][kc * 8] = *(const short8*)(W2T + n * 256 + kc * 8);
    }
    __syncthreads();

    // ---- Phase B: wave w -> rows 16w..16w+15, n-tiles 0..2, K=256
    f4_t accB[3];
#pragma unroll
    for (int n = 0; n < 3; ++n) accB[n] = (f4_t)0.f;
#pragma unroll
    for (int kk = 0; kk < 256; kk += 32) {
        short8 a = *(const short8*)&sH[wv * 16 + l15][kk + quad * 8];
#pragma unroll
        for (int n = 0; n < 3; ++n) {
            short8 b = *(const short8*)&uS.W2s[n * 16 + l15][kk + quad * 8];
            accB[n] = __builtin_amdgcn_mfma_f32_16x16x32_bf16(a, b, accB[n], 0, 0, 0);
        }
    }
    float t0 = temp[0];
#pragma unroll
    for (int n = 0; n < 3; ++n) {
        int col = n * 16 + l15;
        if (col < N_CLS) {
            float bb = b2[col];
#pragma unroll
            for (int r = 0; r < 4; ++r) {
                int grow = rbase + wv * 16 + quad * 4 + r;
                if (grow < N_NODES) {
                    float v = accB[n][r] + bb;
                    h[grow * N_CLS + col] = v;
                    TH[grow * N_CLS + col] = t0 * v;
                }
            }
        }
    }
}

// ---------------------------------------------------------------- propagation
// Pull-based CSR SpMM. 10 threads/node x 4 classes (float4), unroll-4 for ILP.
__global__ __launch_bounds__(256) void prop_kernel(const float* __restrict__ h,
                                                   float* __restrict__ hn,
                                                   const int* __restrict__ rowptr,
                                                   const int* __restrict__ esrc,
                                                   const float* __restrict__ enorm,
                                                   float* __restrict__ TH,
                                                   const float* __restrict__ temp,
                                                   int kidx) {
    int gid = blockIdx.x * 256 + threadIdx.x;
    int v = gid / 10;
    if (v >= N_NODES) return;
    int c = (gid - v * 10) * 4;
    int s = rowptr[v], e = rowptr[v + 1];
    f4_t acc = (f4_t)0.f;
    int j = s;
    for (; j + 4 <= e; j += 4) {
        int u0 = esrc[j], u1 = esrc[j + 1], u2 = esrc[j + 2], u3 = esrc[j + 3];
        float w0 = enorm[j], w1 = enorm[j + 1], w2 = enorm[j + 2], w3 = enorm[j + 3];
        f4_t h0 = *(const f4_t*)(h + u0 * N_CLS + c);
        f4_t h1 = *(const f4_t*)(h + u1 * N_CLS + c);
        f4_t h2 = *(const f4_t*)(h + u2 * N_CLS + c);
        f4_t h3 = *(const f4_t*)(h + u3 * N_CLS + c);
        acc += w0 * h0 + w1 * h1 + w2 * h2 + w3 * h3;
    }
    for (; j < e; ++j) {
        int u = esrc[j];
        float w = enorm[j];
        acc += w * *(const f4_t*)(h + u * N_CLS + c);
    }
    float tk = temp[kidx];
    *(f4_t*)(hn + v * N_CLS + c) = acc;
    f4_t* pt = (f4_t*)(TH + v * N_CLS + c);
    *pt = *pt + tk * acc;
}

// ---------------------------------------------------------------- log_softmax
__global__ __launch_bounds__(256) void lsm_kernel(float* __restrict__ out) {
    int wid = (blockIdx.x * 256 + threadIdx.x) >> 6;
    int lane = threadIdx.x & 63;
    if (wid >= N_NODES) return;
    float x = (lane < N_CLS) ? out[wid * N_CLS + lane] : -INFINITY;
    float m = x;
#pragma unroll
    for (int o = 32; o > 0; o >>= 1) m = fmaxf(m, __shfl_xor(m, o, 64));
    float e = (lane < N_CLS) ? expf(x - m) : 0.f;
    float s = e;
#pragma unroll
    for (int o = 32; o > 0; o >>= 1) s += __shfl_xor(s, o, 64);
    float r = x - m - logf(s);
    if (lane < N_CLS) out[wid * N_CLS + lane] = r;
}

// ---------------------------------------------------------------- launch

extern "C" void kernel_launch(void* const* d_in, const int* in_sizes, int n_in,
                              void* d_out, int out_size, void* d_ws, size_t ws_size,
                              hipStream_t stream) {
    const float* feat = (const float*)d_in[0];
    const float* W1   = (const float*)d_in[1];
    const float* b1   = (const float*)d_in[2];
    const float* W2   = (const float*)d_in[3];
    const float* b2   = (const float*)d_in[4];
    const float* temp = (const float*)d_in[5];
    const int*   src  = (const int*)d_in[6];
    const int*   dst  = (const int*)d_in[7];
    float* out = (float*)d_out;

    // workspace layout (bytes). deg region is reused for W1T/W2T after scan.
    char* ws = (char*)d_ws;
    int*   deg    = (int*)(ws + 0);          //  400000 B (dead after scan)
    short* W1T    = (short*)(ws + 0);        //  262144 B (overlaps deg)
    short* W2T    = (short*)(ws + 262144);   //   32768 B (end 294912 < 400000)
    float* dnorm  = (float*)(ws + 400000);   //  400000 B
    int*   rowptr = (int*)(ws + 800000);     //  400004 B
    int*   cursor = (int*)(ws + 1200016);    //  400000 B
    int*   esrc   = (int*)(ws + 1600032);    // 6800000 B
    float* enorm  = (float*)(ws + 8400032);  // 6800000 B
    float* h0     = (float*)(ws + 15200032); // 16000000 B
    float* h1     = (float*)(ws + 31200032); // 16000000 B  -> end 47200032

    init_deg_kernel<<<(N_NODES + 255) / 256, 256, 0, stream>>>(deg);
    count_dst_kernel<<<(N_EDGES + 255) / 256, 256, 0, stream>>>(dst, deg);
    rsqrt_deg_kernel<<<(N_NODES + 255) / 256, 256, 0, stream>>>(deg, dnorm);
    scan_kernel<<<1, 1024, 0, stream>>>(deg, rowptr, cursor);
    // deg is dead now; convert weights into its space
    cvt_w1_kernel<<<512, 256, 0, stream>>>(W1, W1T);
    cvt_w2_kernel<<<64, 256, 0, stream>>>(W2, W2T);
    scatter_edges_kernel<<<(N_EDGES + 255) / 256, 256, 0, stream>>>(src, dst, dnorm, cursor,
                                                                    esrc, enorm);
    scatter_self_kernel<<<(N_NODES + 255) / 256, 256, 0, stream>>>(dnorm, cursor, esrc, enorm);

    mlp_kernel<<<(N_NODES + 63) / 64, 256, 0, stream>>>(feat, W1T, b1, W2T, b2, temp, h0, out);

    float* hc = h0;
    float* hn = h1;
    for (int k = 0; k < K_HOPS; ++k) {
        prop_kernel<<<(N_NODES * 10 + 255) / 256, 256, 0, stream>>>(hc, hn, rowptr, esrc,
                                                                    enorm, out, temp, k + 1);
        float* t = hc; hc = hn; hn = t;
    }

    lsm_kernel<<<(N_NODES / 4), 256, 0, stream>>>(out);
}

// Round 3
// 1139.842 us; speedup vs baseline: 2.0991x; 1.2127x over previous
//
#include <hip/hip_runtime.h>
#include <math.h>

#define N_NODES 100000
#define N_FEAT  512
#define HIDDEN  256
#define N_CLS   40
#define N_EDGES 1600000
#define K_HOPS  10
#define SCAN_BLOCKS 98  // 98*1024 = 100352 >= N_NODES+1

typedef __attribute__((ext_vector_type(8))) short short8;   // 8 bf16 (one MFMA frag)
typedef __attribute__((ext_vector_type(4))) float f4_t;

__device__ __forceinline__ short f2bf(float f) {
    union { float f; unsigned u; } x; x.f = f;
    unsigned r = x.u + 0x7fffu + ((x.u >> 16) & 1u);  // RNE
    return (short)(r >> 16);
}

// ---------------------------------------------------------------- prep kernels

__global__ __launch_bounds__(256) void init_deg_kernel(int* __restrict__ deg) {
    int v = blockIdx.x * 256 + threadIdx.x;
    if (v < N_NODES) deg[v] = 1;  // self-loop
}

__global__ __launch_bounds__(256) void count_dst_kernel(const int* __restrict__ dst,
                                                        int* __restrict__ deg) {
    int e = blockIdx.x * 256 + threadIdx.x;
    if (e < N_EDGES) atomicAdd(&deg[dst[e]], 1);
}

__global__ __launch_bounds__(256) void rsqrt_deg_kernel(const int* __restrict__ deg,
                                                        float* __restrict__ d) {
    int v = blockIdx.x * 256 + threadIdx.x;
    if (v < N_NODES) d[v] = rsqrtf((float)deg[v]);
}

// ---- 3-phase device-wide exclusive scan of deg -> rowptr/cursor (coalesced)

__global__ __launch_bounds__(1024) void scan_partial_kernel(const int* __restrict__ deg,
                                                            int* __restrict__ blocksum) {
    __shared__ int s[1024];
    int t = threadIdx.x;
    int idx = blockIdx.x * 1024 + t;
    s[t] = (idx < N_NODES) ? deg[idx] : 0;
    __syncthreads();
#pragma unroll
    for (int off = 512; off > 0; off >>= 1) {
        if (t < off) s[t] += s[t + off];
        __syncthreads();
    }
    if (t == 0) blocksum[blockIdx.x] = s[0];
}

__global__ __launch_bounds__(64) void scan_blocks_kernel(const int* __restrict__ blocksum,
                                                         int* __restrict__ blockoff) {
    if (threadIdx.x == 0) {
        int run = 0;
        for (int b = 0; b < SCAN_BLOCKS; ++b) { blockoff[b] = run; run += blocksum[b]; }
    }
}

__global__ __launch_bounds__(1024) void scan_write_kernel(const int* __restrict__ deg,
                                                          const int* __restrict__ blockoff,
                                                          int* __restrict__ rowptr,
                                                          int* __restrict__ cursor) {
    __shared__ int s[1024];
    int t = threadIdx.x;
    int idx = blockIdx.x * 1024 + t;
    int v = (idx < N_NODES) ? deg[idx] : 0;
    s[t] = v;
    __syncthreads();
    // Hillis-Steele inclusive scan
#pragma unroll
    for (int off = 1; off < 1024; off <<= 1) {
        int add = (t >= off) ? s[t - off] : 0;
        __syncthreads();
        s[t] += add;
        __syncthreads();
    }
    int pre = s[t] - v + blockoff[blockIdx.x];  // exclusive prefix
    if (idx <= N_NODES) rowptr[idx] = pre;
    if (idx < N_NODES) cursor[idx] = pre;
}

__global__ __launch_bounds__(256) void scatter_edges_kernel(const int* __restrict__ src,
                                                            const int* __restrict__ dst,
                                                            const float* __restrict__ d,
                                                            int* __restrict__ cursor,
                                                            int* __restrict__ esrc,
                                                            float* __restrict__ enorm) {
    int e = blockIdx.x * 256 + threadIdx.x;
    if (e >= N_EDGES) return;
    int u = src[e], v = dst[e];
    int pos = atomicAdd(&cursor[v], 1);
    esrc[pos] = u;
    enorm[pos] = d[u] * d[v];
}

__global__ __launch_bounds__(256) void scatter_self_kernel(const float* __restrict__ d,
                                                           int* __restrict__ cursor,
                                                           int* __restrict__ esrc,
                                                           float* __restrict__ enorm) {
    int v = blockIdx.x * 256 + threadIdx.x;
    if (v >= N_NODES) return;
    int pos = atomicAdd(&cursor[v], 1);
    esrc[pos] = v;
    float dv = d[v];
    enorm[pos] = dv * dv;
}

// W1 [512][256] f32 -> W1T [256][512] bf16 (col-major: per-col k contiguous)
__global__ __launch_bounds__(256) void cvt_w1_kernel(const float* __restrict__ W1,
                                                     short* __restrict__ W1T) {
    int lin = blockIdx.x * 256 + threadIdx.x;  // 131072
    int k = lin >> 8, n = lin & 255;
    W1T[n * 512 + k] = f2bf(W1[lin]);
}

// W2 [256][40] f32 -> W2T [64][256] bf16, rows >=40 zero
__global__ __launch_bounds__(256) void cvt_w2_kernel(const float* __restrict__ W2,
                                                     short* __restrict__ W2T) {
    int lin = blockIdx.x * 256 + threadIdx.x;  // 16384
    int n = lin >> 8, k = lin & 255;
    W2T[lin] = (n < N_CLS) ? f2bf(W2[k * N_CLS + n]) : (short)0;
}

// ---------------------------------------------------------------- fused MLP (MFMA)
// Block = 256 thr (4 waves), 64 rows. Phase A: h1 = relu(feat@W1+b1) -> sH (bf16).
// Phase B: out = sH @ W2 + b2 -> h, TH. 16x16x32 bf16 MFMA throughout.
__global__ __launch_bounds__(256) void mlp_kernel(const float* __restrict__ feat,
                                                  const short* __restrict__ W1T,
                                                  const float* __restrict__ b1,
                                                  const short* __restrict__ W2T,
                                                  const float* __restrict__ b2,
                                                  const float* __restrict__ temp,
                                                  float* __restrict__ h,
                                                  float* __restrict__ TH) {
    __shared__ union {
        struct { short A[64][72]; short B[256][72]; } a;  // 9216 + 36864 B
        short W2s[48][264];                               // 25344 B
    } uS;
    __shared__ short sH[64][264];                         // 33792 B  (total 79872)

    const int tid = threadIdx.x;
    const int rbase = blockIdx.x * 64;
    const int lane = tid & 63;
    const int wv = tid >> 6;       // wave 0..3
    const int quad = lane >> 4;    // 0..3
    const int l15 = lane & 15;

    f4_t acc[4][4];  // [m-tile][n-tile]
#pragma unroll
    for (int m = 0; m < 4; ++m)
#pragma unroll
        for (int n = 0; n < 4; ++n) acc[m][n] = (f4_t)0.f;

    // ---- Phase A: K = 512 in 8 chunks of 64
    const int arow = tid >> 2;     // staging row 0..63
    const int akq = tid & 3;       // k quarter (16 floats)
    for (int kt = 0; kt < 8; ++kt) {
        __syncthreads();
        {   // stage A: feat fp32 -> bf16 LDS [row][k], pad 72
            int grow = rbase + arow;
            f4_t f0 = (f4_t)0.f, f1 = (f4_t)0.f, f2 = (f4_t)0.f, f3 = (f4_t)0.f;
            if (grow < N_NODES) {
                const f4_t* p = (const f4_t*)(feat + grow * N_FEAT + kt * 64 + akq * 16);
                f0 = p[0]; f1 = p[1]; f2 = p[2]; f3 = p[3];
            }
            short8 lo, hi;
            lo[0]=f2bf(f0[0]); lo[1]=f2bf(f0[1]); lo[2]=f2bf(f0[2]); lo[3]=f2bf(f0[3]);
            lo[4]=f2bf(f1[0]); lo[5]=f2bf(f1[1]); lo[6]=f2bf(f1[2]); lo[7]=f2bf(f1[3]);
            hi[0]=f2bf(f2[0]); hi[1]=f2bf(f2[1]); hi[2]=f2bf(f2[2]); hi[3]=f2bf(f2[3]);
            hi[4]=f2bf(f3[0]); hi[5]=f2bf(f3[1]); hi[6]=f2bf(f3[2]); hi[7]=f2bf(f3[3]);
            short8* dstp = (short8*)&uS.a.A[arow][akq * 16];
            dstp[0] = lo; dstp[1] = hi;
        }
        // stage B: W1T[col][kt*64 .. +63] -> LDS [col][k], pad 72
#pragma unroll
        for (int p = 0; p < 8; ++p) {
            int lin = p * 256 + tid;           // 2048 chunks of 8 bf16
            int col = lin >> 3, kc = lin & 7;
            *(short8*)&uS.a.B[col][kc * 8] =
                *(const short8*)(W1T + col * 512 + kt * 64 + kc * 8);
        }
        __syncthreads();
#pragma unroll
        for (int kk = 0; kk < 64; kk += 32) {
            short8 af[4], bf[4];
#pragma unroll
            for (int m = 0; m < 4; ++m)
                af[m] = *(const short8*)&uS.a.A[m * 16 + l15][kk + quad * 8];
#pragma unroll
            for (int n = 0; n < 4; ++n)
                bf[n] = *(const short8*)&uS.a.B[wv * 64 + n * 16 + l15][kk + quad * 8];
#pragma unroll
            for (int m = 0; m < 4; ++m)
#pragma unroll
                for (int n = 0; n < 4; ++n)
                    acc[m][n] = __builtin_amdgcn_mfma_f32_16x16x32_bf16(af[m], bf[n],
                                                                        acc[m][n], 0, 0, 0);
        }
    }
    __syncthreads();  // uS.a fully consumed before W2s overwrite

    // epilogue A: bias + relu -> sH bf16 [row][col] pad 264
#pragma unroll
    for (int n = 0; n < 4; ++n) {
        int col = wv * 64 + n * 16 + l15;
        float bb = b1[col];
#pragma unroll
        for (int m = 0; m < 4; ++m)
#pragma unroll
            for (int r = 0; r < 4; ++r) {
                float v = acc[m][n][r] + bb;
                sH[m * 16 + quad * 4 + r][col] = f2bf(v > 0.f ? v : 0.f);
            }
    }
    // stage W2s: [48][256] bf16 -> LDS pad 264
#pragma unroll
    for (int p = 0; p < 6; ++p) {
        int lin = p * 256 + tid;               // 1536 chunks of 8 bf16
        int n = lin >> 5, kc = lin & 31;
        *(short8*)&uS.W2s[n][kc * 8] = *(const short8*)(W2T + n * 256 + kc * 8);
    }
    __syncthreads();

    // ---- Phase B: wave w -> rows 16w..16w+15, n-tiles 0..2, K=256
    f4_t accB[3];
#pragma unroll
    for (int n = 0; n < 3; ++n) accB[n] = (f4_t)0.f;
#pragma unroll
    for (int kk = 0; kk < 256; kk += 32) {
        short8 a = *(const short8*)&sH[wv * 16 + l15][kk + quad * 8];
#pragma unroll
        for (int n = 0; n < 3; ++n) {
            short8 b = *(const short8*)&uS.W2s[n * 16 + l15][kk + quad * 8];
            accB[n] = __builtin_amdgcn_mfma_f32_16x16x32_bf16(a, b, accB[n], 0, 0, 0);
        }
    }
    float t0 = temp[0];
#pragma unroll
    for (int n = 0; n < 3; ++n) {
        int col = n * 16 + l15;
        if (col < N_CLS) {
            float bb = b2[col];
#pragma unroll
            for (int r = 0; r < 4; ++r) {
                int grow = rbase + wv * 16 + quad * 4 + r;
                if (grow < N_NODES) {
                    float v = accB[n][r] + bb;
                    h[grow * N_CLS + col] = v;
                    TH[grow * N_CLS + col] = t0 * v;
                }
            }
        }
    }
}

// ---------------------------------------------------------------- propagation
// Pull-based CSR SpMM. 10 threads/node x 4 classes (float4), unroll-4 for ILP.
__global__ __launch_bounds__(256) void prop_kernel(const float* __restrict__ h,
                                                   float* __restrict__ hn,
                                                   const int* __restrict__ rowptr,
                                                   const int* __restrict__ esrc,
                                                   const float* __restrict__ enorm,
                                                   float* __restrict__ TH,
                                                   const float* __restrict__ temp,
                                                   int kidx) {
    int gid = blockIdx.x * 256 + threadIdx.x;
    int v = gid / 10;
    if (v >= N_NODES) return;
    int c = (gid - v * 10) * 4;
    int s = rowptr[v], e = rowptr[v + 1];
    f4_t acc = (f4_t)0.f;
    int j = s;
    for (; j + 4 <= e; j += 4) {
        int u0 = esrc[j], u1 = esrc[j + 1], u2 = esrc[j + 2], u3 = esrc[j + 3];
        float w0 = enorm[j], w1 = enorm[j + 1], w2 = enorm[j + 2], w3 = enorm[j + 3];
        f4_t h0 = *(const f4_t*)(h + u0 * N_CLS + c);
        f4_t h1 = *(const f4_t*)(h + u1 * N_CLS + c);
        f4_t h2 = *(const f4_t*)(h + u2 * N_CLS + c);
        f4_t h3 = *(const f4_t*)(h + u3 * N_CLS + c);
        acc += w0 * h0 + w1 * h1 + w2 * h2 + w3 * h3;
    }
    for (; j < e; ++j) {
        int u = esrc[j];
        float w = enorm[j];
        acc += w * *(const f4_t*)(h + u * N_CLS + c);
    }
    float tk = temp[kidx];
    *(f4_t*)(hn + v * N_CLS + c) = acc;
    f4_t* pt = (f4_t*)(TH + v * N_CLS + c);
    *pt = *pt + tk * acc;
}

// ---------------------------------------------------------------- log_softmax
__global__ __launch_bounds__(256) void lsm_kernel(float* __restrict__ out) {
    int wid = (blockIdx.x * 256 + threadIdx.x) >> 6;
    int lane = threadIdx.x & 63;
    if (wid >= N_NODES) return;
    float x = (lane < N_CLS) ? out[wid * N_CLS + lane] : -INFINITY;
    float m = x;
#pragma unroll
    for (int o = 32; o > 0; o >>= 1) m = fmaxf(m, __shfl_xor(m, o, 64));
    float e = (lane < N_CLS) ? expf(x - m) : 0.f;
    float s = e;
#pragma unroll
    for (int o = 32; o > 0; o >>= 1) s += __shfl_xor(s, o, 64);
    float r = x - m - logf(s);
    if (lane < N_CLS) out[wid * N_CLS + lane] = r;
}

// ---------------------------------------------------------------- launch

extern "C" void kernel_launch(void* const* d_in, const int* in_sizes, int n_in,
                              void* d_out, int out_size, void* d_ws, size_t ws_size,
                              hipStream_t stream) {
    const float* feat = (const float*)d_in[0];
    const float* W1   = (const float*)d_in[1];
    const float* b1   = (const float*)d_in[2];
    const float* W2   = (const float*)d_in[3];
    const float* b2   = (const float*)d_in[4];
    const float* temp = (const float*)d_in[5];
    const int*   src  = (const int*)d_in[6];
    const int*   dst  = (const int*)d_in[7];
    float* out = (float*)d_out;

    // workspace layout (bytes). deg region is reused for W1T/W2T after scan.
    char* ws = (char*)d_ws;
    int*   deg    = (int*)(ws + 0);          //  400000 B (dead after scan_write)
    short* W1T    = (short*)(ws + 0);        //  262144 B (overlaps deg)
    short* W2T    = (short*)(ws + 262144);   //   32768 B (end 294912 < 400000)
    float* dnorm  = (float*)(ws + 400000);   //  400000 B
    int*   rowptr = (int*)(ws + 800000);     //  400004 B
    int*   cursor = (int*)(ws + 1200016);    //  400000 B
    int*   esrc   = (int*)(ws + 1600032);    // 6800000 B
    float* enorm  = (float*)(ws + 8400032);  // 6800000 B
    float* h0     = (float*)(ws + 15200032); // 16000000 B
    float* h1     = (float*)(ws + 31200032); // 16000000 B
    int*   blocksum = (int*)(ws + 47200032); //   392 B
    int*   blockoff = (int*)(ws + 47200432); //   392 B  -> end 47200824

    init_deg_kernel<<<(N_NODES + 255) / 256, 256, 0, stream>>>(deg);
    count_dst_kernel<<<(N_EDGES + 255) / 256, 256, 0, stream>>>(dst, deg);
    rsqrt_deg_kernel<<<(N_NODES + 255) / 256, 256, 0, stream>>>(deg, dnorm);
    scan_partial_kernel<<<SCAN_BLOCKS, 1024, 0, stream>>>(deg, blocksum);
    scan_blocks_kernel<<<1, 64, 0, stream>>>(blocksum, blockoff);
    scan_write_kernel<<<SCAN_BLOCKS, 1024, 0, stream>>>(deg, blockoff, rowptr, cursor);
    // deg is dead now; convert weights into its space
    cvt_w1_kernel<<<512, 256, 0, stream>>>(W1, W1T);
    cvt_w2_kernel<<<64, 256, 0, stream>>>(W2, W2T);
    scatter_edges_kernel<<<(N_EDGES + 255) / 256, 256, 0, stream>>>(src, dst, dnorm, cursor,
                                                                    esrc, enorm);
    scatter_self_kernel<<<(N_NODES + 255) / 256, 256, 0, stream>>>(dnorm, cursor, esrc, enorm);

    mlp_kernel<<<(N_NODES + 63) / 64, 256, 0, stream>>>(feat, W1T, b1, W2T, b2, temp, h0, out);

    float* hc = h0;
    float* hn = h1;
    for (int k = 0; k < K_HOPS; ++k) {
        prop_kernel<<<(N_NODES * 10 + 255) / 256, 256, 0, stream>>>(hc, hn, rowptr, esrc,
                                                                    enorm, out, temp, k + 1);
        float* t = hc; hc = hn; hn = t;
    }

    lsm_kernel<<<(N_NODES / 4), 256, 0, stream>>>(out);
}

// Round 4
// 893.258 us; speedup vs baseline: 2.6785x; 1.2761x over previous
//
#include <hip/hip_runtime.h>
#include <math.h>

#define N_NODES 100000
#define N_FEAT  512
#define HIDDEN  256
#define N_CLS   40
#define N_EDGES 1600000
#define K_HOPS  10
#define SCAN_BLOCKS 98   // 98*1024 = 100352 >= N_NODES+1
#define HPAD 64          // padded h row: 64 bf16 = 128 B (2 cache lines)

typedef __attribute__((ext_vector_type(8))) short short8;   // 8 bf16
typedef __attribute__((ext_vector_type(4))) float f4_t;

__device__ __forceinline__ short f2bf(float f) {
    union { float f; unsigned u; } x; x.f = f;
    unsigned r = x.u + 0x7fffu + ((x.u >> 16) & 1u);  // RNE
    return (short)(r >> 16);
}

__device__ __forceinline__ float bf2f(short b) {
    union { unsigned u; float f; } x;
    x.u = ((unsigned)(unsigned short)b) << 16;
    return x.f;
}

// ---------------------------------------------------------------- prep kernels

__global__ __launch_bounds__(256) void init_deg_kernel(int* __restrict__ deg) {
    int v = blockIdx.x * 256 + threadIdx.x;
    if (v < N_NODES) deg[v] = 1;  // self-loop
}

__global__ __launch_bounds__(256) void count_dst_kernel(const int* __restrict__ dst,
                                                        int* __restrict__ deg) {
    int e = blockIdx.x * 256 + threadIdx.x;
    if (e < N_EDGES) atomicAdd(&deg[dst[e]], 1);
}

__global__ __launch_bounds__(256) void rsqrt_deg_kernel(const int* __restrict__ deg,
                                                        float* __restrict__ d) {
    int v = blockIdx.x * 256 + threadIdx.x;
    if (v < N_NODES) d[v] = rsqrtf((float)deg[v]);
}

// ---- 3-phase device-wide exclusive scan of deg -> rowptr/cursor (coalesced)

__global__ __launch_bounds__(1024) void scan_partial_kernel(const int* __restrict__ deg,
                                                            int* __restrict__ blocksum) {
    __shared__ int s[1024];
    int t = threadIdx.x;
    int idx = blockIdx.x * 1024 + t;
    s[t] = (idx < N_NODES) ? deg[idx] : 0;
    __syncthreads();
#pragma unroll
    for (int off = 512; off > 0; off >>= 1) {
        if (t < off) s[t] += s[t + off];
        __syncthreads();
    }
    if (t == 0) blocksum[blockIdx.x] = s[0];
}

__global__ __launch_bounds__(64) void scan_blocks_kernel(const int* __restrict__ blocksum,
                                                         int* __restrict__ blockoff) {
    if (threadIdx.x == 0) {
        int run = 0;
        for (int b = 0; b < SCAN_BLOCKS; ++b) { blockoff[b] = run; run += blocksum[b]; }
    }
}

__global__ __launch_bounds__(1024) void scan_write_kernel(const int* __restrict__ deg,
                                                          const int* __restrict__ blockoff,
                                                          int* __restrict__ rowptr,
                                                          int* __restrict__ cursor) {
    __shared__ int s[1024];
    int t = threadIdx.x;
    int idx = blockIdx.x * 1024 + t;
    int v = (idx < N_NODES) ? deg[idx] : 0;
    s[t] = v;
    __syncthreads();
#pragma unroll
    for (int off = 1; off < 1024; off <<= 1) {
        int add = (t >= off) ? s[t - off] : 0;
        __syncthreads();
        s[t] += add;
        __syncthreads();
    }
    int pre = s[t] - v + blockoff[blockIdx.x];  // exclusive prefix
    if (idx <= N_NODES) rowptr[idx] = pre;
    if (idx < N_NODES) cursor[idx] = pre;
}

__global__ __launch_bounds__(256) void scatter_edges_kernel(const int* __restrict__ src,
                                                            const int* __restrict__ dst,
                                                            const float* __restrict__ d,
                                                            int* __restrict__ cursor,
                                                            int2* __restrict__ epair) {
    int e = blockIdx.x * 256 + threadIdx.x;
    if (e >= N_EDGES) return;
    int u = src[e], v = dst[e];
    int pos = atomicAdd(&cursor[v], 1);
    int2 p;
    p.x = u;
    p.y = __float_as_int(d[u] * d[v]);
    epair[pos] = p;
}

__global__ __launch_bounds__(256) void scatter_self_kernel(const float* __restrict__ d,
                                                           int* __restrict__ cursor,
                                                           int2* __restrict__ epair) {
    int v = blockIdx.x * 256 + threadIdx.x;
    if (v >= N_NODES) return;
    int pos = atomicAdd(&cursor[v], 1);
    float dv = d[v];
    int2 p;
    p.x = v;
    p.y = __float_as_int(dv * dv);
    epair[pos] = p;
}

// W1 [512][256] f32 -> W1T [256][512] bf16 (col-major: per-col k contiguous)
__global__ __launch_bounds__(256) void cvt_w1_kernel(const float* __restrict__ W1,
                                                     short* __restrict__ W1T) {
    int lin = blockIdx.x * 256 + threadIdx.x;  // 131072
    int k = lin >> 8, n = lin & 255;
    W1T[n * 512 + k] = f2bf(W1[lin]);
}

// W2 [256][40] f32 -> W2T [64][256] bf16, rows >=40 zero
__global__ __launch_bounds__(256) void cvt_w2_kernel(const float* __restrict__ W2,
                                                     short* __restrict__ W2T) {
    int lin = blockIdx.x * 256 + threadIdx.x;  // 16384
    int n = lin >> 8, k = lin & 255;
    W2T[lin] = (n < N_CLS) ? f2bf(W2[k * N_CLS + n]) : (short)0;
}

// ---------------------------------------------------------------- fused MLP (MFMA)
// Block = 256 thr (4 waves), 64 rows. Phase A: h1 = relu(feat@W1+b1) -> sH (bf16).
// Phase B: out = sH @ W2 + b2 -> h (bf16, HPAD rows), TH (fp32).
__global__ __launch_bounds__(256) void mlp_kernel(const float* __restrict__ feat,
                                                  const short* __restrict__ W1T,
                                                  const float* __restrict__ b1,
                                                  const short* __restrict__ W2T,
                                                  const float* __restrict__ b2,
                                                  const float* __restrict__ temp,
                                                  short* __restrict__ h,
                                                  float* __restrict__ TH) {
    __shared__ union {
        struct { short A[64][72]; short B[256][72]; } a;  // 9216 + 36864 B
        short W2s[48][264];                               // 25344 B
    } uS;
    __shared__ short sH[64][264];                         // 33792 B

    const int tid = threadIdx.x;
    const int rbase = blockIdx.x * 64;
    const int lane = tid & 63;
    const int wv = tid >> 6;       // wave 0..3
    const int quad = lane >> 4;    // 0..3
    const int l15 = lane & 15;

    f4_t acc[4][4];
#pragma unroll
    for (int m = 0; m < 4; ++m)
#pragma unroll
        for (int n = 0; n < 4; ++n) acc[m][n] = (f4_t)0.f;

    const int arow = tid >> 2;
    const int akq = tid & 3;
    for (int kt = 0; kt < 8; ++kt) {
        __syncthreads();
        {
            int grow = rbase + arow;
            f4_t f0 = (f4_t)0.f, f1 = (f4_t)0.f, f2 = (f4_t)0.f, f3 = (f4_t)0.f;
            if (grow < N_NODES) {
                const f4_t* p = (const f4_t*)(feat + grow * N_FEAT + kt * 64 + akq * 16);
                f0 = p[0]; f1 = p[1]; f2 = p[2]; f3 = p[3];
            }
            short8 lo, hi;
            lo[0]=f2bf(f0[0]); lo[1]=f2bf(f0[1]); lo[2]=f2bf(f0[2]); lo[3]=f2bf(f0[3]);
            lo[4]=f2bf(f1[0]); lo[5]=f2bf(f1[1]); lo[6]=f2bf(f1[2]); lo[7]=f2bf(f1[3]);
            hi[0]=f2bf(f2[0]); hi[1]=f2bf(f2[1]); hi[2]=f2bf(f2[2]); hi[3]=f2bf(f2[3]);
            hi[4]=f2bf(f3[0]); hi[5]=f2bf(f3[1]); hi[6]=f2bf(f3[2]); hi[7]=f2bf(f3[3]);
            short8* dstp = (short8*)&uS.a.A[arow][akq * 16];
            dstp[0] = lo; dstp[1] = hi;
        }
#pragma unroll
        for (int p = 0; p < 8; ++p) {
            int lin = p * 256 + tid;
            int col = lin >> 3, kc = lin & 7;
            *(short8*)&uS.a.B[col][kc * 8] =
                *(const short8*)(W1T + col * 512 + kt * 64 + kc * 8);
        }
        __syncthreads();
#pragma unroll
        for (int kk = 0; kk < 64; kk += 32) {
            short8 af[4], bf[4];
#pragma unroll
            for (int m = 0; m < 4; ++m)
                af[m] = *(const short8*)&uS.a.A[m * 16 + l15][kk + quad * 8];
#pragma unroll
            for (int n = 0; n < 4; ++n)
                bf[n] = *(const short8*)&uS.a.B[wv * 64 + n * 16 + l15][kk + quad * 8];
#pragma unroll
            for (int m = 0; m < 4; ++m)
#pragma unroll
                for (int n = 0; n < 4; ++n)
                    acc[m][n] = __builtin_amdgcn_mfma_f32_16x16x32_bf16(af[m], bf[n],
                                                                        acc[m][n], 0, 0, 0);
        }
    }
    __syncthreads();

#pragma unroll
    for (int n = 0; n < 4; ++n) {
        int col = wv * 64 + n * 16 + l15;
        float bb = b1[col];
#pragma unroll
        for (int m = 0; m < 4; ++m)
#pragma unroll
            for (int r = 0; r < 4; ++r) {
                float v = acc[m][n][r] + bb;
                sH[m * 16 + quad * 4 + r][col] = f2bf(v > 0.f ? v : 0.f);
            }
    }
#pragma unroll
    for (int p = 0; p < 6; ++p) {
        int lin = p * 256 + tid;
        int n = lin >> 5, kc = lin & 31;
        *(short8*)&uS.W2s[n][kc * 8] = *(const short8*)(W2T + n * 256 + kc * 8);
    }
    __syncthreads();

    f4_t accB[3];
#pragma unroll
    for (int n = 0; n < 3; ++n) accB[n] = (f4_t)0.f;
#pragma unroll
    for (int kk = 0; kk < 256; kk += 32) {
        short8 a = *(const short8*)&sH[wv * 16 + l15][kk + quad * 8];
#pragma unroll
        for (int n = 0; n < 3; ++n) {
            short8 b = *(const short8*)&uS.W2s[n * 16 + l15][kk + quad * 8];
            accB[n] = __builtin_amdgcn_mfma_f32_16x16x32_bf16(a, b, accB[n], 0, 0, 0);
        }
    }
    float t0 = temp[0];
#pragma unroll
    for (int n = 0; n < 3; ++n) {
        int col = n * 16 + l15;
        if (col < N_CLS) {
            float bb = b2[col];
#pragma unroll
            for (int r = 0; r < 4; ++r) {
                int grow = rbase + wv * 16 + quad * 4 + r;
                if (grow < N_NODES) {
                    float v = accB[n][r] + bb;
                    h[grow * HPAD + col] = f2bf(v);
                    TH[grow * N_CLS + col] = t0 * v;
                }
            }
        }
    }
}

// ---------------------------------------------------------------- propagation
// Pull-based CSR SpMM, bf16 h with 128B-padded rows. 5 threads/node x 8 classes.
__global__ __launch_bounds__(256) void prop_kernel(const short* __restrict__ h,
                                                   short* __restrict__ hn,
                                                   const int* __restrict__ rowptr,
                                                   const int2* __restrict__ epair,
                                                   float* __restrict__ TH,
                                                   const float* __restrict__ temp,
                                                   int kidx) {
    int gid = blockIdx.x * 256 + threadIdx.x;
    int v = gid / 5;
    if (v >= N_NODES) return;
    int c = gid - v * 5;  // class chunk 0..4 (8 classes each)
    int s = rowptr[v], e = rowptr[v + 1];
    f4_t a0 = (f4_t)0.f, a1 = (f4_t)0.f;
    int j = s;
    for (; j + 4 <= e; j += 4) {
        int2 e0 = epair[j], e1 = epair[j + 1], e2 = epair[j + 2], e3 = epair[j + 3];
        short8 h0 = *(const short8*)(h + e0.x * HPAD + c * 8);
        short8 h1 = *(const short8*)(h + e1.x * HPAD + c * 8);
        short8 h2 = *(const short8*)(h + e2.x * HPAD + c * 8);
        short8 h3 = *(const short8*)(h + e3.x * HPAD + c * 8);
        float w0 = __int_as_float(e0.y), w1 = __int_as_float(e1.y);
        float w2 = __int_as_float(e2.y), w3 = __int_as_float(e3.y);
#pragma unroll
        for (int i = 0; i < 4; ++i) {
            a0[i] += w0 * bf2f(h0[i]) + w1 * bf2f(h1[i]) + w2 * bf2f(h2[i]) + w3 * bf2f(h3[i]);
            a1[i] += w0 * bf2f(h0[4 + i]) + w1 * bf2f(h1[4 + i]) + w2 * bf2f(h2[4 + i]) +
                     w3 * bf2f(h3[4 + i]);
        }
    }
    for (; j < e; ++j) {
        int2 ep = epair[j];
        short8 hb = *(const short8*)(h + ep.x * HPAD + c * 8);
        float w = __int_as_float(ep.y);
#pragma unroll
        for (int i = 0; i < 4; ++i) {
            a0[i] += w * bf2f(hb[i]);
            a1[i] += w * bf2f(hb[4 + i]);
        }
    }
    float tk = temp[kidx];
    short8 ob;
#pragma unroll
    for (int i = 0; i < 4; ++i) { ob[i] = f2bf(a0[i]); ob[4 + i] = f2bf(a1[i]); }
    *(short8*)(hn + v * HPAD + c * 8) = ob;
    f4_t* pt = (f4_t*)(TH + v * N_CLS + c * 8);
    pt[0] += tk * a0;
    pt[1] += tk * a1;
}

// ---------------------------------------------------------------- log_softmax
__global__ __launch_bounds__(256) void lsm_kernel(float* __restrict__ out) {
    int wid = (blockIdx.x * 256 + threadIdx.x) >> 6;
    int lane = threadIdx.x & 63;
    if (wid >= N_NODES) return;
    float x = (lane < N_CLS) ? out[wid * N_CLS + lane] : -INFINITY;
    float m = x;
#pragma unroll
    for (int o = 32; o > 0; o >>= 1) m = fmaxf(m, __shfl_xor(m, o, 64));
    float e = (lane < N_CLS) ? expf(x - m) : 0.f;
    float s = e;
#pragma unroll
    for (int o = 32; o > 0; o >>= 1) s += __shfl_xor(s, o, 64);
    float r = x - m - logf(s);
    if (lane < N_CLS) out[wid * N_CLS + lane] = r;
}

// ---------------------------------------------------------------- launch

extern "C" void kernel_launch(void* const* d_in, const int* in_sizes, int n_in,
                              void* d_out, int out_size, void* d_ws, size_t ws_size,
                              hipStream_t stream) {
    const float* feat = (const float*)d_in[0];
    const float* W1   = (const float*)d_in[1];
    const float* b1   = (const float*)d_in[2];
    const float* W2   = (const float*)d_in[3];
    const float* b2   = (const float*)d_in[4];
    const float* temp = (const float*)d_in[5];
    const int*   src  = (const int*)d_in[6];
    const int*   dst  = (const int*)d_in[7];
    float* out = (float*)d_out;

    // workspace layout (bytes). deg region reused for W1T/W2T after scan.
    char* ws = (char*)d_ws;
    int*   deg    = (int*)(ws + 0);          //  400000 B (dead after scan_write)
    short* W1T    = (short*)(ws + 0);        //  262144 B (overlaps deg)
    short* W2T    = (short*)(ws + 262144);   //   32768 B
    float* dnorm  = (float*)(ws + 400000);   //  400000 B
    int*   rowptr = (int*)(ws + 800000);     //  400004 B
    int*   cursor = (int*)(ws + 1200016);    //  400000 B
    int2*  epair  = (int2*)(ws + 1600032);   // 13600000 B
    short* h0     = (short*)(ws + 15200032); // 12800000 B (bf16, HPAD rows)
    short* h1     = (short*)(ws + 28000032); // 12800000 B
    int*   blocksum = (int*)(ws + 40800032); //   392 B
    int*   blockoff = (int*)(ws + 40800432); //   392 B  -> end 40800824

    init_deg_kernel<<<(N_NODES + 255) / 256, 256, 0, stream>>>(deg);
    count_dst_kernel<<<(N_EDGES + 255) / 256, 256, 0, stream>>>(dst, deg);
    rsqrt_deg_kernel<<<(N_NODES + 255) / 256, 256, 0, stream>>>(deg, dnorm);
    scan_partial_kernel<<<SCAN_BLOCKS, 1024, 0, stream>>>(deg, blocksum);
    scan_blocks_kernel<<<1, 64, 0, stream>>>(blocksum, blockoff);
    scan_write_kernel<<<SCAN_BLOCKS, 1024, 0, stream>>>(deg, blockoff, rowptr, cursor);
    cvt_w1_kernel<<<512, 256, 0, stream>>>(W1, W1T);
    cvt_w2_kernel<<<64, 256, 0, stream>>>(W2, W2T);
    scatter_edges_kernel<<<(N_EDGES + 255) / 256, 256, 0, stream>>>(src, dst, dnorm, cursor,
                                                                    epair);
    scatter_self_kernel<<<(N_NODES + 255) / 256, 256, 0, stream>>>(dnorm, cursor, epair);

    mlp_kernel<<<(N_NODES + 63) / 64, 256, 0, stream>>>(feat, W1T, b1, W2T, b2, temp, h0, out);

    short* hc = h0;
    short* hn = h1;
    for (int k = 0; k < K_HOPS; ++k) {
        prop_kernel<<<(N_NODES * 5 + 255) / 256, 256, 0, stream>>>(hc, hn, rowptr, epair,
                                                                   out, temp, k + 1);
        short* t = hc; hc = hn; hn = t;
    }

    lsm_kernel<<<(N_NODES / 4), 256, 0, stream>>>(out);
}